// Round 9
// baseline (1042.188 us; speedup 1.0000x reference)
//
#include <hip/hip_runtime.h>
#include <hip/hip_bf16.h>
#include <stdint.h>
#include <stddef.h>

typedef __bf16 bf16;
typedef bf16  bf16x4 __attribute__((ext_vector_type(4)));
typedef bf16  bf16x8 __attribute__((ext_vector_type(8)));
typedef float f32x4  __attribute__((ext_vector_type(4)));

// ---------------------------------------------------------------------------
// async global->LDS, 16B per lane. LDS dest is wave-uniform base + lane*16.
// ---------------------------------------------------------------------------
__device__ __forceinline__ void async_copy16(bf16* lds, const bf16* g) {
    __builtin_amdgcn_global_load_lds(
        (const __attribute__((address_space(1))) void*)g,
        (__attribute__((address_space(3))) void*)lds,
        16, 0, 0);
}

__device__ __forceinline__ void bar() { __builtin_amdgcn_s_barrier(); }
#define SFENCE() __builtin_amdgcn_sched_barrier(0)
#define WAIT_VM4() do { asm volatile("s_waitcnt vmcnt(4)"); SFENCE(); } while (0)
#define WAIT_VM0() do { asm volatile("s_waitcnt vmcnt(0)"); SFENCE(); } while (0)

// ---------------------------------------------------------------------------
// cast fp32 -> bf16, 4 elems/thread (unchanged)
// ---------------------------------------------------------------------------
__global__ __launch_bounds__(256) void cast_f32_to_bf16(
        const float* __restrict__ in, bf16* __restrict__ out, int n4) {
    int i = blockIdx.x * blockDim.x + threadIdx.x;
    if (i >= n4) return;
    const float4 v = *(const float4*)(in + (size_t)i * 4);
    bf16x4 o;
    o[0] = (bf16)v.x; o[1] = (bf16)v.y; o[2] = (bf16)v.z; o[3] = (bf16)v.w;
    *(bf16x4*)(out + (size_t)i * 4) = o;
}

// ---------------------------------------------------------------------------
// W_eff[n][k] = (q[n][k] - 7.5) * scale[n][k/64] + sum_r A[k][r]*Bm[r][n]
// (unchanged)
// ---------------------------------------------------------------------------
__global__ __launch_bounds__(256) void dequant_lora(
        const int*   __restrict__ q,
        const float* __restrict__ scale,
        const float* __restrict__ A,
        const float* __restrict__ Bm,
        bf16* __restrict__ out,
        int N, int K) {
    const int tid = threadIdx.x;
    const int k0 = blockIdx.x * 64;
    const int n0 = blockIdx.y * 64;
    const int kk = k0 + (tid & 15) * 4;
    const int nb = n0 + (tid >> 4) * 4;

    f32x4 Ar[4][4];
    #pragma unroll
    for (int i = 0; i < 4; ++i)
        #pragma unroll
        for (int rq = 0; rq < 4; ++rq)
            Ar[i][rq] = *(const f32x4*)&A[(size_t)(kk + i) * 16 + rq * 4];
    f32x4 Br[16];
    #pragma unroll
    for (int r = 0; r < 16; ++r)
        Br[r] = *(const f32x4*)&Bm[(size_t)r * N + nb];

    const int scol = (unsigned)k0 >> 6;
    #pragma unroll
    for (int nn = 0; nn < 4; ++nn) {
        const int n = nb + nn;
        const int4 qv = *(const int4*)&q[(size_t)n * K + kk];
        const float s = scale[(size_t)n * (K >> 6) + scol];
        float l0 = 0.f, l1 = 0.f, l2 = 0.f, l3 = 0.f;
        #pragma unroll
        for (int r = 0; r < 16; ++r) {
            const float bv = Br[r][nn];
            l0 += Ar[0][r >> 2][r & 3] * bv;
            l1 += Ar[1][r >> 2][r & 3] * bv;
            l2 += Ar[2][r >> 2][r & 3] * bv;
            l3 += Ar[3][r >> 2][r & 3] * bv;
        }
        bf16x4 o;
        o[0] = (bf16)(((float)qv.x - 7.5f) * s + l0);
        o[1] = (bf16)(((float)qv.y - 7.5f) * s + l1);
        o[2] = (bf16)(((float)qv.z - 7.5f) * s + l2);
        o[3] = (bf16)(((float)qv.w - 7.5f) * s + l3);
        *(bf16x4*)&out[(size_t)n * K + kk] = o;
    }
}

// ---------------------------------------------------------------------------
// gemm_bt256 v12: ONE-PHASE-AHEAD READ PIPELINING, zero extra registers.
//
// Rounds 1-8 showed all variants stuck at ~5650 cyc/K-tile = LDS-reads(2310)
// + LDS-writes(512) + MFMA(2483) + barriers, STRICTLY SERIAL: every phase
// read its own operands then MFMA'd them (LDS pipe idle during MFMA, matrix
// pipe idle during reads). v7's read-ahead attempt died of spills (+64 VGPR).
//
// v12 re-splits the phases along (m-half x k-slice) so read-ahead costs ZERO
// extra registers:  p1: A0xB0  p2: A1xB0  p3: A0'xB1  p4: A1'xB1
// where A0=fa03, A1=fa47, B0=fbks0, B1=fbks1; each phase's operands live in
// one of 4 banks (16 VGPR each, 64 total = v8's budget) with disjoint
// lifetimes. Reads (issued at phase top, consumed by the NEXT phase's MFMA,
// 4/8/4/8 per wave): p1: A1ks0(t)  p2: A0ks1(t)+B1=fbks1(t)  p3: A1ks1(t)
// p4 (after vmcnt+bar): A0ks0(t+1)+B0=fbks0(t+1). The LDS pipe drains each
// batch under the current phase's MFMA cluster -> phase ~ max(620, LDS).
//
// Staging (barrier-clean: a region's last LDS reads are lgkm-drained by a
// preceding MFMA before the stage issues):
//   p1: stage A(t+1) (4 copies)   [old A(t-1) reads drained by p4(t-1) MFMA]
//   p4: stage B(t+2) (4 copies)   [fbks1(t) drained by p3 MFMA]
// vmcnt ledger at p4(t): pending = B(t+1)[4 @p4(t-1)] + A(t+1)[4 @p1(t)]
// + B(t+2)[4 @p4(t)] = 12; vmcnt(4) retires 8 = ALL of tile t+1; then
// barrier (all waves drained -> t+1 visible) -> t+1 reads -> MFMA p4.
// Tail: t+2>=NT skips B-stage, vmcnt(0); t+1>=NT skips reads/stage.
// ---------------------------------------------------------------------------
template <bool RELU, typename OUT_T>
__global__ __launch_bounds__(512, 2) void gemm_bt256(
        const bf16* __restrict__ A, const bf16* __restrict__ B,
        const float* __restrict__ bias, OUT_T* __restrict__ C,
        int M, int N, int K) {
    __shared__ __attribute__((aligned(16))) bf16 As0[2][8192];
    __shared__ __attribute__((aligned(16))) bf16 As1[2][8192];
    __shared__ __attribute__((aligned(16))) bf16 Bs0[2][8192];
    __shared__ __attribute__((aligned(16))) bf16 Bs1[2][8192];

    const int tid  = threadIdx.x;
    const int wave = tid >> 6;
    const int lane = tid & 63;
    const int wm   = wave >> 2;     // 0..1 : row half of the 256-tile
    const int wn   = wave & 3;      // 0..3 : 64-col slice
    const int bn   = blockIdx.x;
    const int bm   = blockIdx.y;

    // staging: thread covers 16B-granules tid (rows 0..63) and tid+512
    // (rows 64..127) of each [128][64] half-tile; source col granule
    // pre-swizzled with the same involution the reads apply.
    const int srow = tid >> 3;
    const int scol = ((tid & 7) ^ (srow & 7)) * 8;   // elems
    const bf16* gA = A + ((size_t)(bm * 256) + srow) * K + scol;
    const bf16* gB = B + ((size_t)(bn * 256) + srow) * K + scol;

    auto stage2 = [&](bf16* halfBase, const bf16* g) {
        bf16* l = halfBase + wave * 512;             // wave-uniform dest
        async_copy16(l, g);
        async_copy16(l + 4096, g + (size_t)64 * K);  // rows +64
    };

    const int fr  = lane & 15;
    const int kq  = lane >> 4;
    const int cg0 = ((kq    ) ^ (fr & 7)) * 8;
    const int cg1 = ((kq + 4) ^ (fr & 7)) * 8;
    const int ra  = fr * 64;
    const int rb  = (wn & 1) * 4096 + fr * 64;       // 64-col offset in B half

    f32x4 acc[8][4];
    #pragma unroll
    for (int i = 0; i < 8; ++i)
        #pragma unroll
        for (int j = 0; j < 4; ++j) {
            f32x4 z = {0.f, 0.f, 0.f, 0.f};
            acc[i][j] = z;
        }

    // prologue: stage A(0), B(0), B(1) (12 copies); retire A(0)+B(0).
    stage2(&As0[0][0], gA);
    stage2(&As0[1][0], gA + (size_t)128 * K);
    stage2(&Bs0[0][0], gB);
    stage2(&Bs0[1][0], gB + (size_t)128 * K);
    stage2(&Bs1[0][0], gB + 64);
    stage2(&Bs1[1][0], gB + (size_t)128 * K + 64);
    WAIT_VM4();
    bar();

    const int NT = K >> 6;
    bf16x8 rA0[4], rA1[4], rB0[4], rB1[4];

    // prologue reads (the "p4(t=-1)" batch): A0ks0(0), fbks0(0)
    {
        const bf16* aC = &As0[wm][0];
        const bf16* bC = &Bs0[wn >> 1][0];
        #pragma unroll
        for (int i = 0; i < 4; ++i)
            rA0[i] = *(const bf16x8*)(aC + i * 1024 + ra + cg0);
        #pragma unroll
        for (int j = 0; j < 4; ++j)
            rB0[j] = *(const bf16x8*)(bC + rb + j * 1024 + cg0);
    }

    for (int t0 = 0; t0 < NT; t0 += 2) {
        #pragma unroll
        for (int u = 0; u < 2; ++u) {
            const int t = t0 + u;
            bf16 (*AsC)[8192] = u ? As1 : As0;   // cur dbuf (t&1 == u)
            bf16 (*AsN)[8192] = u ? As0 : As1;   // next dbuf
            bf16 (*BsC)[8192] = u ? Bs1 : Bs0;
            bf16 (*BsN)[8192] = u ? Bs0 : Bs1;
            const bf16* aC = &AsC[wm][0];
            const bf16* bC = &BsC[wn >> 1][0];
            const bf16* aN = &AsN[wm][0];
            const bf16* bN = &BsN[wn >> 1][0];

            // ---- p1: stage A(t+1); read A1<-fa47ks0(t) | MFMA A0xB0 -----
            if (t + 1 < NT) {
                stage2(&AsN[0][0], gA + (size_t)(t + 1) * 64);
                stage2(&AsN[1][0], gA + (size_t)128 * K + (size_t)(t + 1) * 64);
            }
            #pragma unroll
            for (int i = 0; i < 4; ++i)
                rA1[i] = *(const bf16x8*)(aC + (i + 4) * 1024 + ra + cg0);
            bar();
            __builtin_amdgcn_s_setprio(1);
            #pragma unroll
            for (int i = 0; i < 4; ++i)
                #pragma unroll
                for (int j = 0; j < 4; ++j)
                    acc[i][j] = __builtin_amdgcn_mfma_f32_16x16x32_bf16(
                        rA0[i], rB0[j], acc[i][j], 0, 0, 0);
            __builtin_amdgcn_s_setprio(0);
            bar();

            // ---- p2: read A0<-fa03ks1(t), B1<-fbks1(t) | MFMA A1xB0 -----
            #pragma unroll
            for (int i = 0; i < 4; ++i)
                rA0[i] = *(const bf16x8*)(aC + i * 1024 + ra + cg1);
            #pragma unroll
            for (int j = 0; j < 4; ++j)
                rB1[j] = *(const bf16x8*)(bC + rb + j * 1024 + cg1);
            bar();
            __builtin_amdgcn_s_setprio(1);
            #pragma unroll
            for (int i = 0; i < 4; ++i)
                #pragma unroll
                for (int j = 0; j < 4; ++j)
                    acc[i + 4][j] = __builtin_amdgcn_mfma_f32_16x16x32_bf16(
                        rA1[i], rB0[j], acc[i + 4][j], 0, 0, 0);
            __builtin_amdgcn_s_setprio(0);
            bar();

            // ---- p3: read A1<-fa47ks1(t) | MFMA A0xB1 -------------------
            #pragma unroll
            for (int i = 0; i < 4; ++i)
                rA1[i] = *(const bf16x8*)(aC + (i + 4) * 1024 + ra + cg1);
            bar();
            __builtin_amdgcn_s_setprio(1);
            #pragma unroll
            for (int i = 0; i < 4; ++i)
                #pragma unroll
                for (int j = 0; j < 4; ++j)
                    acc[i][j] = __builtin_amdgcn_mfma_f32_16x16x32_bf16(
                        rA0[i], rB1[j], acc[i][j], 0, 0, 0);
            __builtin_amdgcn_s_setprio(0);
            bar();

            // ---- p4: stage B(t+2); vmcnt; bar; read t+1 | MFMA A1xB1 ----
            if (t + 2 < NT) {
                stage2(&BsC[0][0], gB + (size_t)(t + 2) * 64);
                stage2(&BsC[1][0], gB + (size_t)128 * K + (size_t)(t + 2) * 64);
                WAIT_VM4();          // retires ALL of tile t+1 (8 of 12)
            } else if (t + 1 < NT) {
                WAIT_VM0();          // tail: everything pending = tile t+1
            }
            bar();                   // all waves drained -> t+1 visible
            if (t + 1 < NT) {
                #pragma unroll
                for (int i = 0; i < 4; ++i)
                    rA0[i] = *(const bf16x8*)(aN + i * 1024 + ra + cg0);
                #pragma unroll
                for (int j = 0; j < 4; ++j)
                    rB0[j] = *(const bf16x8*)(bN + rb + j * 1024 + cg0);
            }
            __builtin_amdgcn_s_setprio(1);
            #pragma unroll
            for (int i = 0; i < 4; ++i)
                #pragma unroll
                for (int j = 0; j < 4; ++j)
                    acc[i + 4][j] = __builtin_amdgcn_mfma_f32_16x16x32_bf16(
                        rA1[i], rB1[j], acc[i + 4][j], 0, 0, 0);
            __builtin_amdgcn_s_setprio(0);
            bar();
        }
    }

    // epilogue: C/D layout col = lane&15, row = (lane>>4)*4 + reg (verified)
    const int er = bm * 256 + wm * 128 + (lane >> 4) * 4;
    const int ec = bn * 256 + wn * 64 + fr;
    #pragma unroll
    for (int j = 0; j < 4; ++j) {
        const int col = ec + j * 16;
        const float bv = bias[col];
        #pragma unroll
        for (int i = 0; i < 8; ++i) {
            #pragma unroll
            for (int r = 0; r < 4; ++r) {
                const int row = er + i * 16 + r;
                float v = acc[i][j][r] + bv;
                if (RELU) v = v > 0.f ? v : 0.f;
                C[(size_t)row * N + col] = (OUT_T)v;
            }
        }
    }
}

// ---------------------------------------------------------------------------
extern "C" void kernel_launch(void* const* d_in, const int* in_sizes, int n_in,
                              void* d_out, int out_size, void* d_ws, size_t ws_size,
                              hipStream_t stream) {
    const float* x1           = (const float*)d_in[0];
    const int*   w_up_q       = (const int*)  d_in[1];
    const float* w_up_scale   = (const float*)d_in[2];
    const float* b_up         = (const float*)d_in[3];
    const float* w_up_lora_a  = (const float*)d_in[4];
    const float* w_up_lora_b  = (const float*)d_in[5];
    const int*   w_down_q     = (const int*)  d_in[6];
    const float* w_down_scale = (const float*)d_in[7];
    const float* b_down       = (const float*)d_in[8];
    const float* w_down_lora_a= (const float*)d_in[9];
    const float* w_down_lora_b= (const float*)d_in[10];
    float* out = (float*)d_out;

    const int M = 8192, D = 2048, H = 8192;

    char* ws = (char*)d_ws;
    bf16* x1b = (bf16*)ws;                                   // M*D   (32 MB)
    bf16* wup = (bf16*)(ws + (size_t)M * D * 2);             // H*D   (32 MB)
    bf16* x2  = (bf16*)(ws + (size_t)M * D * 2 + (size_t)H * D * 2); // M*H (128 MB)
    bf16* wdn = x1b;  // reuse region 0 after gemm1 consumed x1b

    {
        int n4 = (M * D) / 4;
        cast_f32_to_bf16<<<dim3((n4 + 255) / 256), dim3(256), 0, stream>>>(x1, x1b, n4);
    }
    dequant_lora<<<dim3(D / 64, H / 64), dim3(256), 0, stream>>>(
        w_up_q, w_up_scale, w_up_lora_a, w_up_lora_b, wup, H, D);
    gemm_bt256<true, bf16><<<dim3(H / 256, M / 256), dim3(512), 0, stream>>>(
        x1b, wup, b_up, x2, M, H, D);
    dequant_lora<<<dim3(H / 64, D / 64), dim3(256), 0, stream>>>(
        w_down_q, w_down_scale, w_down_lora_a, w_down_lora_b, wdn, D, H);
    gemm_bt256<false, float><<<dim3(D / 256, M / 256), dim3(512), 0, stream>>>(
        x2, wdn, b_down, out, M, D, H);
}